// Round 15
// baseline (206.673 us; speedup 1.0000x reference)
//
#include <hip/hip_runtime.h>
#include <hip/hip_bf16.h>

#define N_NODES 50000
#define N_EDGES 1600000
#define C_IN 19
#define C_OUT 128
#define NPB 40                                // nodes per block in node_transform
#define TBLOCKS (N_NODES / NPB)               // 1250
#define CAP 92                                // slots per node (mean deg 32)
#define NBUCK 391                             // dst buckets: bucket = dst >> 7
#define BNODE 128                             // nodes per bucket
#define EPB 2560                              // edges per partition block
#define PBLK (N_EDGES / EPB)                  // 625 blocks per graph
#define P3T 320                               // p3 threads (5 waves); EPB/P3T = 8
#define NCOL (2 * NBUCK)                      // 782 (graph, bucket) columns
#define COLCAP 4608                           // fixed records per column window (+8 sigma)

typedef unsigned short ushort_t;
typedef unsigned int uint_t;

__device__ __forceinline__ float sigmoidf(float v) { return 1.0f / (1.0f + expf(-v)); }

// rec format (4B): src[31:16] | dl[15:9] | w9[8:0]

// Node transform: NPB nodes per 128-thread block, weights in regs, folded
// attention scalars computed in-block from staged LDS weights.
__global__ __launch_bounds__(128) void node_transform(
    const float* __restrict__ x,
    const float* __restrict__ Wh, const float* __restrict__ bh,
    const float* __restrict__ aWh, const float* __restrict__ abh,
    const float* __restrict__ Wk, const float* __restrict__ bk,
    const float* __restrict__ aWk, const float* __restrict__ abk,
    __hip_bfloat16* __restrict__ xt_h, __hip_bfloat16* __restrict__ xt_k,
    float* __restrict__ sh_i, float* __restrict__ sh_j,
    float* __restrict__ sk_i, float* __restrict__ sk_j)
{
    __shared__ float sW[2 * C_OUT * C_IN];    // 4864 floats (19.5 KB)
    __shared__ float xrow[NPB * C_IN];        // 760 floats
    __shared__ float su[80];

    const int c = threadIdx.x;

    const float4* Wh4 = reinterpret_cast<const float4*>(Wh);
    const float4* Wk4 = reinterpret_cast<const float4*>(Wk);
    float4* sW4 = reinterpret_cast<float4*>(sW);
    for (int i = c; i < 608; i += 128) { sW4[i] = Wh4[i]; sW4[608 + i] = Wk4[i]; }

    const int base_n = blockIdx.x * NPB;
    const float4* x4 = reinterpret_cast<const float4*>(x + (size_t)base_n * C_IN);
    float4* xr4 = reinterpret_cast<float4*>(xrow);
    for (int i = c; i < NPB * C_IN / 4; i += 128) xr4[i] = x4[i];
    __syncthreads();

    float wh[C_IN], wk[C_IN];
#pragma unroll
    for (int k = 0; k < C_IN; ++k) {
        wh[k] = sW[c * C_IN + k];
        wk[k] = sW[2432 + c * C_IN + k];
    }
    const float bhc = bh[c], bkc = bk[c];

    for (int i = 0; i < NPB; ++i) {
        float ah = bhc, ak = bkc;
#pragma unroll
        for (int k = 0; k < C_IN; ++k) {
            const float xv = xrow[i * C_IN + k];
            ah = fmaf(xv, wh[k], ah);
            ak = fmaf(xv, wk[k], ak);
        }
        const int n = base_n + i;
        xt_h[(size_t)n * C_OUT + c] = __float2bfloat16(ah);
        xt_k[(size_t)n * C_OUT + c] = __float2bfloat16(ak);
    }

    // in-block fold: su[v*19+k] = sum_c aW[v-half][c] * W[c][k]; su[76..79] = bias dots
    if (c < 76) {
        const int v = c / 19, k = c % 19;
        const float* aW = (v < 2) ? aWh : aWk;
        const float* Wbase = sW + ((v < 2) ? 0 : 2432);
        const int half = (v & 1) * C_OUT;
        float s = 0.f;
        for (int cc = 0; cc < C_OUT; ++cc)
            s = fmaf(aW[half + cc], Wbase[cc * C_IN + k], s);
        su[c] = s;
    } else if (c < 80) {
        const int v = c - 76;
        const float* aW = (v < 2) ? aWh : aWk;
        const float* b = (v < 2) ? bh : bk;
        const int half = (v & 1) * C_OUT;
        float s = 0.f;
        for (int cc = 0; cc < C_OUT; ++cc)
            s = fmaf(aW[half + cc], b[cc], s);
        if ((v & 1) == 0) s += (v < 2) ? abh[0] : abk[0];
        su[c] = s;
    }
    __syncthreads();

    for (int i = c; i < NPB; i += 128) {
        const int n = base_n + i;
        float s0 = su[76], s1 = su[77], s2 = su[78], s3 = su[79];
#pragma unroll
        for (int k = 0; k < C_IN; ++k) {
            const float xv = xrow[i * C_IN + k];
            s0 = fmaf(xv, su[k], s0);
            s1 = fmaf(xv, su[19 + k], s1);
            s2 = fmaf(xv, su[38 + k], s2);
            s3 = fmaf(xv, su[57 + k], s3);
        }
        sh_i[n] = s0; sh_j[n] = s1; sk_i[n] = s2; sk_j[n] = s3;
    }
}

// P3: self-allocating partition. Each block: local LDS histogram of its 2560
// edges -> one global atomicAdd per non-empty bucket to reserve a chunk in the
// fixed column window -> partition into the private chunk (LDS-atomic rank,
// plain stores). No separate histogram kernel, no scan kernel.
__global__ __launch_bounds__(P3T) void p3_part(
    const int* __restrict__ hei, const int* __restrict__ kei,
    const float* __restrict__ sh_i, const float* __restrict__ sh_j,
    const float* __restrict__ sk_i, const float* __restrict__ sk_j,
    int* __restrict__ colcur,
    uint_t* __restrict__ part32)
{
    const int g = blockIdx.x >= PBLK;
    const int blk = blockIdx.x - g * PBLK;
    const int* ei = g ? kei : hei;
    const float* s_i = g ? sk_i : sh_i;
    const float* s_j = g ? sk_j : sh_j;

    __shared__ int hist[NBUCK];
    __shared__ int gbase[NBUCK];
    const int t = threadIdx.x;
    for (int i = t; i < NBUCK; i += P3T) hist[i] = 0;
    __syncthreads();

    const int base = blk * EPB;
    const int4* src4 = reinterpret_cast<const int4*>(ei + base);
    const int4* dst4 = reinterpret_cast<const int4*>(ei + N_EDGES + base);
    const int4 sa = src4[t], sb = src4[t + P3T];
    const int4 da = dst4[t], db = dst4[t + P3T];

    int s[8] = {sa.x, sa.y, sa.z, sa.w, sb.x, sb.y, sb.z, sb.w};
    int d[8] = {da.x, da.y, da.z, da.w, db.x, db.y, db.z, db.w};

    // local histogram
#pragma unroll
    for (int i = 0; i < 8; ++i) atomicAdd(&hist[d[i] >> 7], 1);

    // overlap: fetch scalars + sigmoid while histogram settles
    float si[8], sj[8];
#pragma unroll
    for (int i = 0; i < 8; ++i) { si[i] = s_i[d[i]]; sj[i] = s_j[s[i]]; }
    uint_t w9[8];
#pragma unroll
    for (int i = 0; i < 8; ++i)
        w9[i] = (uint_t)(sigmoidf(si[i] + sj[i]) * 511.f + 0.5f);
    __syncthreads();

    // reserve chunks (one global atomic per non-empty bucket), reset cursors
    for (int i = t; i < NBUCK; i += P3T) {
        const int h = hist[i];
        gbase[i] = h ? atomicAdd(&colcur[g * NBUCK + i], h) : 0;
    }
    __syncthreads();
    for (int i = t; i < NBUCK; i += P3T) hist[i] = 0;
    __syncthreads();

    // partition into private chunks
#pragma unroll
    for (int i = 0; i < 8; ++i) {
        const int b = d[i] >> 7;
        const int r = atomicAdd(&hist[b], 1);
        const int off = gbase[b] + r;
        if (off < COLCAP) {
            const size_t col = (size_t)(g * NBUCK + b);
            part32[col * COLCAP + off] =
                ((uint_t)s[i] << 16) | ((uint_t)(d[i] & 127) << 9) | w9[i];
        }
    }
}

// P4: one block per (graph, bucket): LDS per-node rank, write final slotted
// records (4B) into the bucket's window + per-node counts. 4 recs/iter ILP.
__global__ __launch_bounds__(256) void p4_final(
    const uint_t* __restrict__ part32,
    const int* __restrict__ colcur,
    uint_t* __restrict__ finrec, int* __restrict__ cnt)
{
    const int col = blockIdx.x;               // g*NBUCK + b
    const int g = col >= NBUCK;
    const int b = col - g * NBUCK;
    __shared__ int cur[BNODE];
    const int t = threadIdx.x;
    if (t < BNODE) cur[t] = 0;
    __syncthreads();
    const int start = col * COLCAP;
    int len = colcur[col];
    len = len < COLCAP ? len : COLCAP;
    const size_t fbase = (size_t)(g * N_NODES + (b << 7)) * CAP;

    int i = t;
    for (; i + 768 < len; i += 1024) {
        const uint_t v0 = part32[start + i];
        const uint_t v1 = part32[start + i + 256];
        const uint_t v2 = part32[start + i + 512];
        const uint_t v3 = part32[start + i + 768];
        const int d0 = (v0 >> 9) & 127, d1 = (v1 >> 9) & 127;
        const int d2 = (v2 >> 9) & 127, d3 = (v3 >> 9) & 127;
        const int r0 = atomicAdd(&cur[d0], 1);
        const int r1 = atomicAdd(&cur[d1], 1);
        const int r2 = atomicAdd(&cur[d2], 1);
        const int r3 = atomicAdd(&cur[d3], 1);
        if (r0 < CAP) finrec[fbase + (size_t)d0 * CAP + r0] = v0;
        if (r1 < CAP) finrec[fbase + (size_t)d1 * CAP + r1] = v1;
        if (r2 < CAP) finrec[fbase + (size_t)d2 * CAP + r2] = v2;
        if (r3 < CAP) finrec[fbase + (size_t)d3 * CAP + r3] = v3;
    }
    for (; i < len; i += 256) {
        const uint_t v = part32[start + i];
        const int dl = (v >> 9) & 127;
        const int r = atomicAdd(&cur[dl], 1);
        if (r < CAP) finrec[fbase + (size_t)dl * CAP + r] = v;
    }
    __syncthreads();
    if (t < BNODE) {
        const int node = (b << 7) + t;
        if (node < N_NODES) {
            const int c = cur[t];
            cnt[g * N_NODES + node] = c < CAP ? c : CAP;
        }
    }
}

struct Acc8 { float a0, a1, a2, a3, a4, a5, a6, a7; };

__device__ __forceinline__ void qfma(Acc8& a, const uint4 u, const float wgt)
{
    a.a0 = fmaf(wgt, __uint_as_float(u.x << 16), a.a0);
    a.a1 = fmaf(wgt, __uint_as_float(u.x & 0xffff0000u), a.a1);
    a.a2 = fmaf(wgt, __uint_as_float(u.y << 16), a.a2);
    a.a3 = fmaf(wgt, __uint_as_float(u.y & 0xffff0000u), a.a3);
    a.a4 = fmaf(wgt, __uint_as_float(u.z << 16), a.a4);
    a.a5 = fmaf(wgt, __uint_as_float(u.z & 0xffff0000u), a.a5);
    a.a6 = fmaf(wgt, __uint_as_float(u.w << 16), a.a6);
    a.a7 = fmaf(wgt, __uint_as_float(u.w & 0xffff0000u), a.a7);
}

// One block (2 waves) per node; wave 0 = hyper, wave 1 = knn.
// 4 edges per VMEM instruction; batch-16 (4 quad-loads in flight).
__global__ __launch_bounds__(128) void gather_gate(
    const __hip_bfloat16* __restrict__ xt_h, const __hip_bfloat16* __restrict__ xt_k,
    const uint_t* __restrict__ finrec, const int* __restrict__ cnt,
    const float* __restrict__ gW, const float* __restrict__ gb,
    float* __restrict__ out)
{
    const int n = blockIdx.x;
    const int tid = threadIdx.x, lane = tid & 63, wid = tid >> 6;
    const int li = lane & 15, q = lane >> 4;       // lane-in-group, quad-group

    const ushort_t* xt = reinterpret_cast<const ushort_t*>(wid ? xt_k : xt_h);
    const uint_t* rec = finrec + (size_t)(wid * N_NODES + n) * CAP;
    const int end = cnt[wid * N_NODES + n];

    Acc8 acc = {0.f, 0.f, 0.f, 0.f, 0.f, 0.f, 0.f, 0.f};
    const uint_t choff = (uint_t)(li << 3);        // 8 channels per lane
    const float wscale = 1.0f / 511.f;

    int p = 0;
    for (; p + 16 <= end; p += 16) {
        const uint_t rv0 = rec[p + q];
        const uint_t rv1 = rec[p + 4 + q];
        const uint_t rv2 = rec[p + 8 + q];
        const uint_t rv3 = rec[p + 12 + q];
        const uint4 u0 = *reinterpret_cast<const uint4*>(xt + (((size_t)(rv0 >> 16)) << 7) + choff);
        const uint4 u1 = *reinterpret_cast<const uint4*>(xt + (((size_t)(rv1 >> 16)) << 7) + choff);
        const uint4 u2 = *reinterpret_cast<const uint4*>(xt + (((size_t)(rv2 >> 16)) << 7) + choff);
        const uint4 u3 = *reinterpret_cast<const uint4*>(xt + (((size_t)(rv3 >> 16)) << 7) + choff);
        const float w0 = (float)(rv0 & 0x1ffu) * wscale;
        const float w1 = (float)(rv1 & 0x1ffu) * wscale;
        const float w2 = (float)(rv2 & 0x1ffu) * wscale;
        const float w3 = (float)(rv3 & 0x1ffu) * wscale;
        qfma(acc, u0, w0); qfma(acc, u1, w1); qfma(acc, u2, w2); qfma(acc, u3, w3);
    }
    for (; p < end; p += 4) {
        const int e = p + q;
        const uint_t rv = rec[e < end ? e : end - 1];
        const float wgt = (e < end) ? (float)(rv & 0x1ffu) * wscale : 0.f;
        const uint4 u = *reinterpret_cast<const uint4*>(xt + (((size_t)(rv >> 16)) << 7) + choff);
        qfma(acc, u, wgt);
    }

    // combine the 4 quad-group partials, then gate
    __shared__ float sacc[2][4][C_OUT + 8];
    *reinterpret_cast<float4*>(&sacc[wid][q][li << 3]) = make_float4(acc.a0, acc.a1, acc.a2, acc.a3);
    *reinterpret_cast<float4*>(&sacc[wid][q][(li << 3) + 4]) = make_float4(acc.a4, acc.a5, acc.a6, acc.a7);
    __syncthreads();

    const float h = sacc[0][0][tid] + sacc[0][1][tid] + sacc[0][2][tid] + sacc[0][3][tid];
    const float k = sacc[1][0][tid] + sacc[1][1][tid] + sacc[1][2][tid] + sacc[1][3][tid];

    float2 part = make_float2(fmaf(h, gW[tid], k * gW[C_OUT + tid]),
                              fmaf(h, gW[2 * C_OUT + tid], k * gW[3 * C_OUT + tid]));
    for (int o = 32; o > 0; o >>= 1) {
        part.x += __shfl_xor(part.x, o);
        part.y += __shfl_xor(part.y, o);
    }
    __shared__ float2 wsum[2];
    __shared__ float gg[2];
    if (lane == 0) wsum[wid] = part;
    __syncthreads();
    if (tid == 0) {
        gg[0] = sigmoidf(wsum[0].x + wsum[1].x + gb[0]);
        gg[1] = sigmoidf(wsum[0].y + wsum[1].y + gb[1]);
    }
    __syncthreads();
    out[(size_t)n * C_OUT + tid] = gg[0] * h + gg[1] * k;
}

extern "C" void kernel_launch(void* const* d_in, const int* in_sizes, int n_in,
                              void* d_out, int out_size, void* d_ws, size_t ws_size,
                              hipStream_t stream) {
    const float* x   = (const float*)d_in[0];
    const int*   hei = (const int*)d_in[1];
    const int*   kei = (const int*)d_in[2];
    const float* hW  = (const float*)d_in[3];
    const float* hb  = (const float*)d_in[4];
    const float* haW = (const float*)d_in[5];
    const float* hab = (const float*)d_in[6];
    const float* kW  = (const float*)d_in[7];
    const float* kb  = (const float*)d_in[8];
    const float* kaW = (const float*)d_in[9];
    const float* kab = (const float*)d_in[10];
    const float* gW  = (const float*)d_in[11];
    const float* gb  = (const float*)d_in[12];
    float* out = (float*)d_out;

    const size_t NC = (size_t)N_NODES * C_OUT;
    char* base = (char*)d_ws;

    __hip_bfloat16* xt_h = (__hip_bfloat16*)base;            // NC * 2B
    __hip_bfloat16* xt_k = xt_h + NC;                        // NC * 2B
    float* sh_i = (float*)(xt_k + NC);                       // 4 * N floats
    float* sh_j = sh_i + N_NODES;
    float* sk_i = sh_j + N_NODES;
    float* sk_j = sk_i + N_NODES;
    int* colcur  = (int*)(sk_j + N_NODES);                   // NCOL ints
    int* cnt     = colcur + NCOL;                            // 2*N ints
    uint_t* part32 = (uint_t*)(cnt + 2 * N_NODES);           // NCOL*COLCAP * 4B (14.4 MB)
    uint_t* finrec = part32 + (size_t)NCOL * COLCAP;         // 2*N*CAP * 4B

    (void)hipMemsetAsync(colcur, 0, NCOL * sizeof(int), stream);

    node_transform<<<TBLOCKS, 128, 0, stream>>>(
        x, hW, hb, haW, hab, kW, kb, kaW, kab,
        xt_h, xt_k, sh_i, sh_j, sk_i, sk_j);

    p3_part<<<2 * PBLK, P3T, 0, stream>>>(
        hei, kei, sh_i, sh_j, sk_i, sk_j,
        colcur, part32);

    p4_final<<<NCOL, 256, 0, stream>>>(
        part32, colcur, finrec, cnt);

    gather_gate<<<N_NODES, 128, 0, stream>>>(
        xt_h, xt_k, finrec, cnt, gW, gb, out);
}

// Round 16
// 193.660 us; speedup vs baseline: 1.0672x; 1.0672x over previous
//
#include <hip/hip_runtime.h>
#include <hip/hip_bf16.h>

#define N_NODES 50000
#define N_EDGES 1600000
#define C_IN 19
#define C_OUT 128
#define NPB 40                                // nodes per block in node_transform
#define TBLOCKS (N_NODES / NPB)               // 1250
#define CAP 92                                // slots per node (mean deg 32)
#define NBUCK 391                             // dst buckets: bucket = dst >> 7
#define BNODE 128                             // nodes per bucket
#define EPB 2560                              // edges per partition/hist block
#define PBLK (N_EDGES / EPB)                  // 625 blocks per graph
#define P3T 320                               // p3 threads (5 waves); EPB/P3T = 8
#define NCOL (2 * NBUCK)                      // 782 (graph, bucket) columns
#define COLCAP 4608                           // fixed records per column window (+8 sigma)
#define SCT 640                               // p2a threads (10 waves >= PBLK)

typedef unsigned short ushort_t;
typedef unsigned int uint_t;

__device__ __forceinline__ float sigmoidf(float v) { return 1.0f / (1.0f + expf(-v)); }

// rec format (4B): src[31:16] | dl[15:9] | w9[8:0]

// Fused: blocks [0,TBLOCKS) = node transform (NPB nodes each, weights in regs,
// folded attention scalars computed in-block from staged LDS weights).
// Blocks [TBLOCKS, TBLOCKS+2*PBLK) = bucket histogram (int4 loads, LDS atomics)
// -- runs overlapped with the transform blocks inside one dispatch.
__global__ __launch_bounds__(128) void node_p1(
    const float* __restrict__ x,
    const float* __restrict__ Wh, const float* __restrict__ bh,
    const float* __restrict__ aWh, const float* __restrict__ abh,
    const float* __restrict__ Wk, const float* __restrict__ bk,
    const float* __restrict__ aWk, const float* __restrict__ abk,
    __hip_bfloat16* __restrict__ xt_h, __hip_bfloat16* __restrict__ xt_k,
    float* __restrict__ sh_i, float* __restrict__ sh_j,
    float* __restrict__ sk_i, float* __restrict__ sk_j,
    const int* __restrict__ hdst, const int* __restrict__ kdst,
    int* __restrict__ counts)
{
    __shared__ float sW[2 * C_OUT * C_IN];    // 4864 floats (19.5 KB)
    __shared__ float xrow[NPB * C_IN];        // 760 floats
    __shared__ float su[80];
    __shared__ int hist[NBUCK];

    const int c = threadIdx.x;

    if (blockIdx.x >= TBLOCKS) {
        const int blk0 = blockIdx.x - TBLOCKS;
        const int g = blk0 >= PBLK;
        const int blk = blk0 - g * PBLK;
        const int* dst = g ? kdst : hdst;
        for (int i = c; i < NBUCK; i += 128) hist[i] = 0;
        __syncthreads();
        const int4* dst4 = reinterpret_cast<const int4*>(dst + blk * EPB);
#pragma unroll
        for (int i = 0; i < 5; ++i) {
            const int4 v = dst4[c + i * 128];
            atomicAdd(&hist[v.x >> 7], 1);
            atomicAdd(&hist[v.y >> 7], 1);
            atomicAdd(&hist[v.z >> 7], 1);
            atomicAdd(&hist[v.w >> 7], 1);
        }
        __syncthreads();
        for (int i = c; i < NBUCK; i += 128)
            counts[(g * NBUCK + i) * PBLK + blk] = hist[i];
        return;
    }

    const float4* Wh4 = reinterpret_cast<const float4*>(Wh);
    const float4* Wk4 = reinterpret_cast<const float4*>(Wk);
    float4* sW4 = reinterpret_cast<float4*>(sW);
    for (int i = c; i < 608; i += 128) { sW4[i] = Wh4[i]; sW4[608 + i] = Wk4[i]; }

    const int base_n = blockIdx.x * NPB;
    const float4* x4 = reinterpret_cast<const float4*>(x + (size_t)base_n * C_IN);
    float4* xr4 = reinterpret_cast<float4*>(xrow);
    for (int i = c; i < NPB * C_IN / 4; i += 128) xr4[i] = x4[i];
    __syncthreads();

    float wh[C_IN], wk[C_IN];
#pragma unroll
    for (int k = 0; k < C_IN; ++k) {
        wh[k] = sW[c * C_IN + k];
        wk[k] = sW[2432 + c * C_IN + k];
    }
    const float bhc = bh[c], bkc = bk[c];

    for (int i = 0; i < NPB; ++i) {
        float ah = bhc, ak = bkc;
#pragma unroll
        for (int k = 0; k < C_IN; ++k) {
            const float xv = xrow[i * C_IN + k];
            ah = fmaf(xv, wh[k], ah);
            ak = fmaf(xv, wk[k], ak);
        }
        const int n = base_n + i;
        xt_h[(size_t)n * C_OUT + c] = __float2bfloat16(ah);
        xt_k[(size_t)n * C_OUT + c] = __float2bfloat16(ak);
    }

    // in-block fold: su[v*19+k] = sum_c aW[v-half][c] * W[c][k]; su[76..79] = bias dots
    if (c < 76) {
        const int v = c / 19, k = c % 19;
        const float* aW = (v < 2) ? aWh : aWk;
        const float* Wbase = sW + ((v < 2) ? 0 : 2432);
        const int half = (v & 1) * C_OUT;
        float s = 0.f;
        for (int cc = 0; cc < C_OUT; ++cc)
            s = fmaf(aW[half + cc], Wbase[cc * C_IN + k], s);
        su[c] = s;
    } else if (c < 80) {
        const int v = c - 76;
        const float* aW = (v < 2) ? aWh : aWk;
        const float* b = (v < 2) ? bh : bk;
        const int half = (v & 1) * C_OUT;
        float s = 0.f;
        for (int cc = 0; cc < C_OUT; ++cc)
            s = fmaf(aW[half + cc], b[cc], s);
        if ((v & 1) == 0) s += (v < 2) ? abh[0] : abk[0];
        su[c] = s;
    }
    __syncthreads();

    for (int i = c; i < NPB; i += 128) {
        const int n = base_n + i;
        float s0 = su[76], s1 = su[77], s2 = su[78], s3 = su[79];
#pragma unroll
        for (int k = 0; k < C_IN; ++k) {
            const float xv = xrow[i * C_IN + k];
            s0 = fmaf(xv, su[k], s0);
            s1 = fmaf(xv, su[19 + k], s1);
            s2 = fmaf(xv, su[38 + k], s2);
            s3 = fmaf(xv, su[57 + k], s3);
        }
        sh_i[n] = s0; sh_j[n] = s1; sk_i[n] = s2; sk_j[n] = s3;
    }
}

// P2a: exclusive scan of each column (length PBLK) via wave shuffle scan
// (2 barriers instead of 20); emit column total.
__global__ __launch_bounds__(SCT) void p2a(int* __restrict__ counts, int* __restrict__ coltot)
{
    const int col = blockIdx.x;               // [0, NCOL)
    const int t = threadIdx.x;
    const int lane = t & 63, w = t >> 6;      // 10 waves
    __shared__ int wtot[SCT / 64];

    const int v = (t < PBLK) ? counts[col * PBLK + t] : 0;
    int inc = v;
    for (int o = 1; o < 64; o <<= 1) {
        const int u = __shfl_up(inc, o);
        if (lane >= o) inc += u;
    }
    if (lane == 63) wtot[w] = inc;
    __syncthreads();
    if (t < SCT / 64) {
        int s = wtot[t];
        int run = s;
        for (int o = 1; o < SCT / 64; o <<= 1) {
            const int u = __shfl_up(run, o, 16);
            if (t >= o) run += u;
        }
        wtot[t] = run - s;                    // exclusive wave offset
    }
    __syncthreads();
    const int ex = inc - v + wtot[w];
    if (t < PBLK) counts[col * PBLK + t] = ex;
    if (t == PBLK - 1) coltot[col] = ex + v;
}

// P3: partition edges into fixed column windows (colstart = col*COLCAP).
// int4 edge loads, 8 edges/thread ILP, LDS atomics for intra-block rank.
__global__ __launch_bounds__(P3T) void p3_part(
    const int* __restrict__ hei, const int* __restrict__ kei,
    const float* __restrict__ sh_i, const float* __restrict__ sh_j,
    const float* __restrict__ sk_i, const float* __restrict__ sk_j,
    const int* __restrict__ counts,
    uint_t* __restrict__ part32)
{
    const int g = blockIdx.x >= PBLK;
    const int blk = blockIdx.x - g * PBLK;
    const int* ei = g ? kei : hei;
    const float* s_i = g ? sk_i : sh_i;
    const float* s_j = g ? sk_j : sh_j;

    __shared__ int cur[NBUCK];
    __shared__ int gbase[NBUCK];
    const int t = threadIdx.x;
    for (int i = t; i < NBUCK; i += P3T) {
        cur[i] = 0;
        gbase[i] = counts[(g * NBUCK + i) * PBLK + blk];   // within-column offset
    }
    __syncthreads();

    const int base = blk * EPB;
    const int4* src4 = reinterpret_cast<const int4*>(ei + base);
    const int4* dst4 = reinterpret_cast<const int4*>(ei + N_EDGES + base);
    const int4 sa = src4[t], sb = src4[t + P3T];
    const int4 da = dst4[t], db = dst4[t + P3T];

    int s[8] = {sa.x, sa.y, sa.z, sa.w, sb.x, sb.y, sb.z, sb.w};
    int d[8] = {da.x, da.y, da.z, da.w, db.x, db.y, db.z, db.w};
    float si[8], sj[8];
#pragma unroll
    for (int i = 0; i < 8; ++i) { si[i] = s_i[d[i]]; sj[i] = s_j[s[i]]; }
    uint_t w9[8];
#pragma unroll
    for (int i = 0; i < 8; ++i)
        w9[i] = (uint_t)(sigmoidf(si[i] + sj[i]) * 511.f + 0.5f);
#pragma unroll
    for (int i = 0; i < 8; ++i) {
        const int b = d[i] >> 7;
        const int r = atomicAdd(&cur[b], 1);
        const int off = gbase[b] + r;
        if (off < COLCAP) {
            const size_t col = (size_t)(g * NBUCK + b);
            part32[col * COLCAP + off] =
                ((uint_t)s[i] << 16) | ((uint_t)(d[i] & 127) << 9) | w9[i];
        }
    }
}

// P4: one block per (graph, bucket): LDS per-node rank, write final slotted
// records (4B) into the bucket's window + per-node counts. 4 recs/iter ILP.
__global__ __launch_bounds__(256) void p4_final(
    const uint_t* __restrict__ part32,
    const int* __restrict__ coltot,
    uint_t* __restrict__ finrec, int* __restrict__ cnt)
{
    const int col = blockIdx.x;               // g*NBUCK + b
    const int g = col >= NBUCK;
    const int b = col - g * NBUCK;
    __shared__ int cur[BNODE];
    const int t = threadIdx.x;
    if (t < BNODE) cur[t] = 0;
    __syncthreads();
    const int start = col * COLCAP;
    int len = coltot[col];
    len = len < COLCAP ? len : COLCAP;
    const size_t fbase = (size_t)(g * N_NODES + (b << 7)) * CAP;

    int i = t;
    for (; i + 768 < len; i += 1024) {
        const uint_t v0 = part32[start + i];
        const uint_t v1 = part32[start + i + 256];
        const uint_t v2 = part32[start + i + 512];
        const uint_t v3 = part32[start + i + 768];
        const int d0 = (v0 >> 9) & 127, d1 = (v1 >> 9) & 127;
        const int d2 = (v2 >> 9) & 127, d3 = (v3 >> 9) & 127;
        const int r0 = atomicAdd(&cur[d0], 1);
        const int r1 = atomicAdd(&cur[d1], 1);
        const int r2 = atomicAdd(&cur[d2], 1);
        const int r3 = atomicAdd(&cur[d3], 1);
        if (r0 < CAP) finrec[fbase + (size_t)d0 * CAP + r0] = v0;
        if (r1 < CAP) finrec[fbase + (size_t)d1 * CAP + r1] = v1;
        if (r2 < CAP) finrec[fbase + (size_t)d2 * CAP + r2] = v2;
        if (r3 < CAP) finrec[fbase + (size_t)d3 * CAP + r3] = v3;
    }
    for (; i < len; i += 256) {
        const uint_t v = part32[start + i];
        const int dl = (v >> 9) & 127;
        const int r = atomicAdd(&cur[dl], 1);
        if (r < CAP) finrec[fbase + (size_t)dl * CAP + r] = v;
    }
    __syncthreads();
    if (t < BNODE) {
        const int node = (b << 7) + t;
        if (node < N_NODES) {
            const int c = cur[t];
            cnt[g * N_NODES + node] = c < CAP ? c : CAP;
        }
    }
}

struct Acc8 { float a0, a1, a2, a3, a4, a5, a6, a7; };

__device__ __forceinline__ void qfma(Acc8& a, const uint4 u, const float wgt)
{
    a.a0 = fmaf(wgt, __uint_as_float(u.x << 16), a.a0);
    a.a1 = fmaf(wgt, __uint_as_float(u.x & 0xffff0000u), a.a1);
    a.a2 = fmaf(wgt, __uint_as_float(u.y << 16), a.a2);
    a.a3 = fmaf(wgt, __uint_as_float(u.y & 0xffff0000u), a.a3);
    a.a4 = fmaf(wgt, __uint_as_float(u.z << 16), a.a4);
    a.a5 = fmaf(wgt, __uint_as_float(u.z & 0xffff0000u), a.a5);
    a.a6 = fmaf(wgt, __uint_as_float(u.w << 16), a.a6);
    a.a7 = fmaf(wgt, __uint_as_float(u.w & 0xffff0000u), a.a7);
}

// One block (2 waves) per node; wave 0 = hyper, wave 1 = knn.
// 4 edges per VMEM instruction; batch-16 (4 quad-loads in flight).
__global__ __launch_bounds__(128) void gather_gate(
    const __hip_bfloat16* __restrict__ xt_h, const __hip_bfloat16* __restrict__ xt_k,
    const uint_t* __restrict__ finrec, const int* __restrict__ cnt,
    const float* __restrict__ gW, const float* __restrict__ gb,
    float* __restrict__ out)
{
    const int n = blockIdx.x;
    const int tid = threadIdx.x, lane = tid & 63, wid = tid >> 6;
    const int li = lane & 15, q = lane >> 4;       // lane-in-group, quad-group

    const ushort_t* xt = reinterpret_cast<const ushort_t*>(wid ? xt_k : xt_h);
    const uint_t* rec = finrec + (size_t)(wid * N_NODES + n) * CAP;
    const int end = cnt[wid * N_NODES + n];

    Acc8 acc = {0.f, 0.f, 0.f, 0.f, 0.f, 0.f, 0.f, 0.f};
    const uint_t choff = (uint_t)(li << 3);        // 8 channels per lane
    const float wscale = 1.0f / 511.f;

    int p = 0;
    for (; p + 16 <= end; p += 16) {
        const uint_t rv0 = rec[p + q];
        const uint_t rv1 = rec[p + 4 + q];
        const uint_t rv2 = rec[p + 8 + q];
        const uint_t rv3 = rec[p + 12 + q];
        const uint4 u0 = *reinterpret_cast<const uint4*>(xt + (((size_t)(rv0 >> 16)) << 7) + choff);
        const uint4 u1 = *reinterpret_cast<const uint4*>(xt + (((size_t)(rv1 >> 16)) << 7) + choff);
        const uint4 u2 = *reinterpret_cast<const uint4*>(xt + (((size_t)(rv2 >> 16)) << 7) + choff);
        const uint4 u3 = *reinterpret_cast<const uint4*>(xt + (((size_t)(rv3 >> 16)) << 7) + choff);
        const float w0 = (float)(rv0 & 0x1ffu) * wscale;
        const float w1 = (float)(rv1 & 0x1ffu) * wscale;
        const float w2 = (float)(rv2 & 0x1ffu) * wscale;
        const float w3 = (float)(rv3 & 0x1ffu) * wscale;
        qfma(acc, u0, w0); qfma(acc, u1, w1); qfma(acc, u2, w2); qfma(acc, u3, w3);
    }
    for (; p < end; p += 4) {
        const int e = p + q;
        const uint_t rv = rec[e < end ? e : end - 1];
        const float wgt = (e < end) ? (float)(rv & 0x1ffu) * wscale : 0.f;
        const uint4 u = *reinterpret_cast<const uint4*>(xt + (((size_t)(rv >> 16)) << 7) + choff);
        qfma(acc, u, wgt);
    }

    // combine the 4 quad-group partials, then gate
    __shared__ float sacc[2][4][C_OUT + 8];
    *reinterpret_cast<float4*>(&sacc[wid][q][li << 3]) = make_float4(acc.a0, acc.a1, acc.a2, acc.a3);
    *reinterpret_cast<float4*>(&sacc[wid][q][(li << 3) + 4]) = make_float4(acc.a4, acc.a5, acc.a6, acc.a7);
    __syncthreads();

    const float h = sacc[0][0][tid] + sacc[0][1][tid] + sacc[0][2][tid] + sacc[0][3][tid];
    const float k = sacc[1][0][tid] + sacc[1][1][tid] + sacc[1][2][tid] + sacc[1][3][tid];

    float2 part = make_float2(fmaf(h, gW[tid], k * gW[C_OUT + tid]),
                              fmaf(h, gW[2 * C_OUT + tid], k * gW[3 * C_OUT + tid]));
    for (int o = 32; o > 0; o >>= 1) {
        part.x += __shfl_xor(part.x, o);
        part.y += __shfl_xor(part.y, o);
    }
    __shared__ float2 wsum[2];
    __shared__ float gg[2];
    if (lane == 0) wsum[wid] = part;
    __syncthreads();
    if (tid == 0) {
        gg[0] = sigmoidf(wsum[0].x + wsum[1].x + gb[0]);
        gg[1] = sigmoidf(wsum[0].y + wsum[1].y + gb[1]);
    }
    __syncthreads();
    out[(size_t)n * C_OUT + tid] = gg[0] * h + gg[1] * k;
}

extern "C" void kernel_launch(void* const* d_in, const int* in_sizes, int n_in,
                              void* d_out, int out_size, void* d_ws, size_t ws_size,
                              hipStream_t stream) {
    const float* x   = (const float*)d_in[0];
    const int*   hei = (const int*)d_in[1];
    const int*   kei = (const int*)d_in[2];
    const float* hW  = (const float*)d_in[3];
    const float* hb  = (const float*)d_in[4];
    const float* haW = (const float*)d_in[5];
    const float* hab = (const float*)d_in[6];
    const float* kW  = (const float*)d_in[7];
    const float* kb  = (const float*)d_in[8];
    const float* kaW = (const float*)d_in[9];
    const float* kab = (const float*)d_in[10];
    const float* gW  = (const float*)d_in[11];
    const float* gb  = (const float*)d_in[12];
    float* out = (float*)d_out;

    const size_t NC = (size_t)N_NODES * C_OUT;
    char* base = (char*)d_ws;

    __hip_bfloat16* xt_h = (__hip_bfloat16*)base;            // NC * 2B
    __hip_bfloat16* xt_k = xt_h + NC;                        // NC * 2B
    float* sh_i = (float*)(xt_k + NC);                       // 4 * N floats
    float* sh_j = sh_i + N_NODES;
    float* sk_i = sh_j + N_NODES;
    float* sk_j = sk_i + N_NODES;
    int* counts   = (int*)(sk_j + N_NODES);                  // NCOL*PBLK ints
    int* coltot   = counts + NCOL * PBLK;                    // NCOL ints
    int* cnt      = coltot + NCOL;                           // 2*N ints
    uint_t* part32 = (uint_t*)(cnt + 2 * N_NODES);           // NCOL*COLCAP * 4B (14.4 MB)
    uint_t* finrec = part32 + (size_t)NCOL * COLCAP;         // 2*N*CAP * 4B

    node_p1<<<TBLOCKS + 2 * PBLK, 128, 0, stream>>>(
        x, hW, hb, haW, hab, kW, kb, kaW, kab,
        xt_h, xt_k, sh_i, sh_j, sk_i, sk_j,
        hei + N_EDGES, kei + N_EDGES, counts);

    p2a<<<NCOL, SCT, 0, stream>>>(counts, coltot);

    p3_part<<<2 * PBLK, P3T, 0, stream>>>(
        hei, kei, sh_i, sh_j, sk_i, sk_j,
        counts, part32);

    p4_final<<<NCOL, 256, 0, stream>>>(
        part32, coltot, finrec, cnt);

    gather_gate<<<N_NODES, 128, 0, stream>>>(
        xt_h, xt_k, finrec, cnt, gW, gb, out);
}